// Round 1
// baseline (870.225 us; speedup 1.0000x reference)
//
#include <hip/hip_runtime.h>

static constexpr int F = 64;   // IN_FEATS == HIDDEN
static constexpr int C = 16;   // NUM_CLASSES

// ---------------------------------------------------------------- degree
__global__ void deg_count(const int* __restrict__ dst, float* __restrict__ deg,
                          int nEdges) {
    int e = blockIdx.x * blockDim.x + threadIdx.x;
    if (e < nEdges) atomicAdd(&deg[dst[e]], 1.0f);
}

// ------------------------------------------------- edge scatter (sum agg)
// one thread per (edge, feature); wave of 64 lanes = one edge
__global__ void scatter_sum(const float* __restrict__ x, const int* __restrict__ src,
                            const int* __restrict__ dst, float* __restrict__ agg,
                            int nEdges) {
    long long tid = (long long)blockIdx.x * blockDim.x + threadIdx.x;
    int e = (int)(tid >> 6);
    int f = (int)(tid & 63);
    if (e >= nEdges) return;
    int s = src[e];
    int d = dst[e];
    atomicAdd(&agg[(long long)d * F + f], x[(long long)s * F + f]);
}

// -------------------------------------------- layer 1: mean -> @W1+b1 -> relu
// block = 256 threads = 4 nodes x 64 output feats
__global__ void layer1(const float* __restrict__ agg, const float* __restrict__ deg,
                       const float* __restrict__ W1, const float* __restrict__ b1,
                       float* __restrict__ h, int nNodes) {
    __shared__ float xs[4][F];
    int g = threadIdx.x >> 6;
    int t = threadIdx.x & 63;
    int node = blockIdx.x * 4 + g;
    if (node < nNodes) {
        float d = fmaxf(deg[node], 1.0f);
        xs[g][t] = agg[(long long)node * F + t] / d;
    }
    __syncthreads();
    if (node >= nNodes) return;
    float acc = b1[t];
#pragma unroll
    for (int k = 0; k < F; ++k) acc = fmaf(xs[g][k], W1[k * F + t], acc);
    h[(long long)node * F + t] = fmaxf(acc, 0.0f);
}

// -------------------------------------------- layer 2: mean -> @W2+b2
// block = 256 threads = 16 nodes x 16 classes
__global__ void layer2(const float* __restrict__ agg, const float* __restrict__ deg,
                       const float* __restrict__ W2, const float* __restrict__ b2,
                       float* __restrict__ out, int nNodes) {
    __shared__ float ys[16][F + 1];   // +1 pad: kills 4-way bank conflict
    int nodeBase = blockIdx.x * 16;
    for (int i = threadIdx.x; i < 16 * F; i += 256) {
        int n = i >> 6, k = i & 63;
        int node = nodeBase + n;
        float v = 0.0f;
        if (node < nNodes) v = agg[(long long)node * F + k] / fmaxf(deg[node], 1.0f);
        ys[n][k] = v;
    }
    __syncthreads();
    int n = threadIdx.x >> 4;
    int c = threadIdx.x & 15;
    int node = nodeBase + n;
    if (node >= nNodes) return;
    float acc = b2[c];
#pragma unroll
    for (int k = 0; k < F; ++k) acc = fmaf(ys[n][k], W2[k * C + c], acc);
    out[(long long)node * C + c] = acc;
}

// ---------------------------------------------------------------- launch
extern "C" void kernel_launch(void* const* d_in, const int* in_sizes, int n_in,
                              void* d_out, int out_size, void* d_ws, size_t ws_size,
                              hipStream_t stream) {
    const float* features = (const float*)d_in[0];
    const int*   src      = (const int*)d_in[1];
    const int*   dst      = (const int*)d_in[2];
    const float* W1       = (const float*)d_in[3];
    const float* b1       = (const float*)d_in[4];
    const float* W2       = (const float*)d_in[5];
    const float* b2       = (const float*)d_in[6];
    float*       out      = (float*)d_out;

    const int nNodes = in_sizes[0] / F;
    const int nEdges = in_sizes[1];

    char* ws = (char*)d_ws;
    float* deg = (float*)ws;
    size_t degBytes = ((size_t)nNodes * sizeof(float) + 255) / 256 * 256;
    float* agg = (float*)(ws + degBytes);            // nNodes * F floats
    float* h   = agg + (size_t)nNodes * F;           // nNodes * F floats

    // zero degree + first aggregation buffer
    hipMemsetAsync(deg, 0, (size_t)nNodes * sizeof(float), stream);
    hipMemsetAsync(agg, 0, (size_t)nNodes * F * sizeof(float), stream);

    deg_count<<<(nEdges + 255) / 256, 256, 0, stream>>>(dst, deg, nEdges);

    long long work = (long long)nEdges * 64;
    int blocks = (int)((work + 255) / 256);
    scatter_sum<<<blocks, 256, 0, stream>>>(features, src, dst, agg, nEdges);

    layer1<<<(nNodes + 3) / 4, 256, 0, stream>>>(agg, deg, W1, b1, h, nNodes);

    hipMemsetAsync(agg, 0, (size_t)nNodes * F * sizeof(float), stream);
    scatter_sum<<<blocks, 256, 0, stream>>>(h, src, dst, agg, nEdges);

    layer2<<<(nNodes + 15) / 16, 256, 0, stream>>>(agg, deg, W2, b2, out, nNodes);
}

// Round 4
// 466.902 us; speedup vs baseline: 1.8638x; 1.8638x over previous
//
#include <hip/hip_runtime.h>

static constexpr int F = 64;   // IN_FEATS == HIDDEN
static constexpr int C = 16;   // NUM_CLASSES

// ---------------------------------------------------------------- degree
__global__ void deg_count(const int* __restrict__ dst, int* __restrict__ deg,
                          int nEdges) {
    int e = blockIdx.x * blockDim.x + threadIdx.x;
    if (e < nEdges) atomicAdd(&deg[dst[e]], 1);
}

// ---------------------------------------------------- scan: block partials
__global__ void scan_part(const int* __restrict__ deg, int* __restrict__ bsum,
                          int nNodes) {
    __shared__ int s[256];
    int i = blockIdx.x * 256 + threadIdx.x;
    s[threadIdx.x] = (i < nNodes) ? deg[i] : 0;
    __syncthreads();
    for (int o = 128; o > 0; o >>= 1) {
        if (threadIdx.x < o) s[threadIdx.x] += s[threadIdx.x + o];
        __syncthreads();
    }
    if (threadIdx.x == 0) bsum[blockIdx.x] = s[0];
}

// ------------------------------------- scan: single-block exclusive (nb<=1024)
__global__ void scan_block(int* __restrict__ bsum, int nb) {
    __shared__ int s[1024];
    int t = threadIdx.x;
    s[t] = (t < nb) ? bsum[t] : 0;
    __syncthreads();
    for (int o = 1; o < 1024; o <<= 1) {
        int v = (t >= o) ? s[t - o] : 0;
        __syncthreads();
        s[t] += v;
        __syncthreads();
    }
    int ex = (t > 0) ? s[t - 1] : 0;
    if (t < nb) bsum[t] = ex;
}

// ------------------- scan: per-element exclusive + offset -> rowstart, cursor
__global__ void scan_final(const int* __restrict__ deg, const int* __restrict__ boff,
                           int* __restrict__ rowstart, int* __restrict__ cursor,
                           int nNodes) {
    __shared__ int s[256];
    int i = blockIdx.x * 256 + threadIdx.x;
    int v = (i < nNodes) ? deg[i] : 0;
    s[threadIdx.x] = v;
    __syncthreads();
    for (int o = 1; o < 256; o <<= 1) {
        int u = (threadIdx.x >= o) ? s[threadIdx.x - o] : 0;
        __syncthreads();
        s[threadIdx.x] += u;
        __syncthreads();
    }
    int ex = boff[blockIdx.x] + ((threadIdx.x > 0) ? s[threadIdx.x - 1] : 0);
    if (i < nNodes) {
        rowstart[i] = ex;
        cursor[i]   = ex;
        if (i == nNodes - 1) rowstart[nNodes] = ex + v;
    }
}

// ------------------------------------------------------ CSR edge placement
__global__ void csr_fill(const int* __restrict__ src, const int* __restrict__ dst,
                         int* __restrict__ cursor, int* __restrict__ csr,
                         int nEdges) {
    int e = blockIdx.x * blockDim.x + threadIdx.x;
    if (e >= nEdges) return;
    int pos = atomicAdd(&cursor[dst[e]], 1);
    csr[pos] = src[e];
}

// -------------------------- agg[node,:] = mean of feature rows (wave/node)
// (byte-identical to round 3 — under test)
__global__ void gather_mean64(const float* __restrict__ x, const int* __restrict__ rowstart,
                              const int* __restrict__ csr, float* __restrict__ agg,
                              int nNodes) {
    int wave = threadIdx.x >> 6, lane = threadIdx.x & 63;
    int node = blockIdx.x * 4 + wave;
    if (node >= nNodes) return;
    int beg = rowstart[node], end = rowstart[node + 1];
    float acc = 0.0f;
    for (int j0 = beg; j0 < end; j0 += 64) {
        int cnt = min(64, end - j0);
        int idx = (j0 + lane < end) ? csr[j0 + lane] : 0;
        for (int k = 0; k < cnt; ++k) {
            int s = __shfl(idx, k);
            acc += x[(size_t)s * F + lane];
        }
    }
    agg[(size_t)node * F + lane] = acc / fmaxf((float)(end - beg), 1.0f);
}

// ---------------- layer1 in-place: agg = relu(agg @ W1 + b1)  (4 nodes/block)
__global__ void layer1_inplace(float* __restrict__ agg, const float* __restrict__ W1,
                               const float* __restrict__ b1, int nNodes) {
    __shared__ float xs[4][F];
    int g = threadIdx.x >> 6, t = threadIdx.x & 63;
    int node = blockIdx.x * 4 + g;
    if (node < nNodes) xs[g][t] = agg[(size_t)node * F + t];
    __syncthreads();
    if (node >= nNodes) return;
    float acc = b1[t];
#pragma unroll
    for (int k = 0; k < F; ++k) acc = fmaf(xs[g][k], W1[k * F + t], acc);
    agg[(size_t)node * F + t] = fmaxf(acc, 0.0f);   // safe: row staged above
}

// -------------------------------------------------------- t2 = h @ W2
__global__ void mm2(const float* __restrict__ h, const float* __restrict__ W,
                    float* __restrict__ y, int nNodes) {
    __shared__ float ys[16][F + 1];
    int nodeBase = blockIdx.x * 16;
    for (int i = threadIdx.x; i < 16 * F; i += 256) {
        int n = i >> 6, k = i & 63;
        int node = nodeBase + n;
        ys[n][k] = (node < nNodes) ? h[(size_t)node * F + k] : 0.0f;
    }
    __syncthreads();
    int n = threadIdx.x >> 4, c = threadIdx.x & 15;
    int node = nodeBase + n;
    if (node >= nNodes) return;
    float acc = 0.0f;
#pragma unroll
    for (int k = 0; k < F; ++k) acc = fmaf(ys[n][k], W[k * C + c], acc);
    y[(size_t)node * C + c] = acc;
}

// ------------------- layer-2 aggregation via PROVEN atomic scatter (16-wide)
__global__ void scatter16(const float* __restrict__ t2, const int* __restrict__ src,
                          const int* __restrict__ dst, float* __restrict__ acc2,
                          int nEdges) {
    long long tid = (long long)blockIdx.x * blockDim.x + threadIdx.x;
    int e = (int)(tid >> 4);
    int c = (int)(tid & 15);
    if (e >= nEdges) return;
    atomicAdd(&acc2[(size_t)dst[e] * C + c], t2[(size_t)src[e] * C + c]);
}

// ------------------------------------ out = acc2/deg + b2 (deg from rowstart)
__global__ void finish2(const float* __restrict__ acc2, const int* __restrict__ rowstart,
                        const float* __restrict__ b2, float* __restrict__ out,
                        int nNodes) {
    int tid = blockIdx.x * blockDim.x + threadIdx.x;
    if (tid >= nNodes * C) return;
    int node = tid >> 4, c = tid & 15;
    float d = fmaxf((float)(rowstart[node + 1] - rowstart[node]), 1.0f);
    out[tid] = acc2[tid] / d + b2[c];
}

// ---------------------------------------------------------------- launch
extern "C" void kernel_launch(void* const* d_in, const int* in_sizes, int n_in,
                              void* d_out, int out_size, void* d_ws, size_t ws_size,
                              hipStream_t stream) {
    const float* features = (const float*)d_in[0];
    const int*   src      = (const int*)d_in[1];
    const int*   dst      = (const int*)d_in[2];
    const float* W1       = (const float*)d_in[3];
    const float* b1       = (const float*)d_in[4];
    const float* W2       = (const float*)d_in[5];
    const float* b2       = (const float*)d_in[6];
    float*       out      = (float*)d_out;

    const int nNodes = in_sizes[0] / F;
    const int nEdges = in_sizes[1];
    const int NB = (nNodes + 255) / 256;   // 391 <= 1024

    // ---- workspace carve-up (peak 46.0 MiB; round-1 proved >=51 MiB works)
    char* ws = (char*)d_ws;
    auto align = [](size_t x) { return (x + 255) / 256 * 256; };
    int* deg      = (int*)ws;      ws += align((size_t)nNodes * 4);
    int* rowstart = (int*)ws;      ws += align((size_t)(nNodes + 1) * 4);
    int* cursor   = (int*)ws;      ws += align((size_t)nNodes * 4);
    int* bsum     = (int*)ws;      ws += align((size_t)NB * 4);
    int* csr      = (int*)ws;      ws += align((size_t)nEdges * 4);
    float* agg    = (float*)ws;    ws += align((size_t)nNodes * F * 4);   // also h
    float* t2     = (float*)ws;    ws += align((size_t)nNodes * C * 4);
    float* acc2   = (float*)ws;    ws += align((size_t)nNodes * C * 4);

    hipMemsetAsync(deg, 0, (size_t)nNodes * sizeof(int), stream);
    hipMemsetAsync(acc2, 0, (size_t)nNodes * C * sizeof(float), stream);

    // ---- CSR build (dst-sorted adjacency) — byte-identical to round 3
    deg_count<<<(nEdges + 255) / 256, 256, 0, stream>>>(dst, deg, nEdges);
    scan_part<<<NB, 256, 0, stream>>>(deg, bsum, nNodes);
    scan_block<<<1, 1024, 0, stream>>>(bsum, NB);
    scan_final<<<NB, 256, 0, stream>>>(deg, bsum, rowstart, cursor, nNodes);
    csr_fill<<<(nEdges + 255) / 256, 256, 0, stream>>>(src, dst, cursor, csr, nEdges);

    // ---- layer 1: agg = mean_agg(features); agg = relu(agg@W1 + b1) in-place
    gather_mean64<<<(nNodes + 3) / 4, 256, 0, stream>>>(features, rowstart, csr, agg, nNodes);
    layer1_inplace<<<(nNodes + 3) / 4, 256, 0, stream>>>(agg, W1, b1, nNodes);

    // ---- layer 2: t2 = h@W2; acc2 = scatter-sum(t2); out = acc2/deg + b2
    mm2<<<(nNodes + 15) / 16, 256, 0, stream>>>(agg, W2, t2, nNodes);
    {
        long long work = (long long)nEdges * C;
        int blocks = (int)((work + 255) / 256);
        scatter16<<<blocks, 256, 0, stream>>>(t2, src, dst, acc2, nEdges);
    }
    finish2<<<(nNodes * C + 255) / 256, 256, 0, stream>>>(acc2, rowstart, b2, out, nNodes);
}

// Round 5
// 400.632 us; speedup vs baseline: 2.1721x; 1.1654x over previous
//
#include <hip/hip_runtime.h>

static constexpr int F = 64;   // IN_FEATS == HIDDEN
static constexpr int C = 16;   // NUM_CLASSES

// ---------------------------------------------------------------- degree
__global__ void deg_count(const int* __restrict__ dst, int* __restrict__ deg,
                          int nEdges) {
    int e = blockIdx.x * blockDim.x + threadIdx.x;
    if (e < nEdges) atomicAdd(&deg[dst[e]], 1);
}

// ---------------------------------------------------- scan: block partials
__global__ void scan_part(const int* __restrict__ deg, int* __restrict__ bsum,
                          int nNodes) {
    __shared__ int s[256];
    int i = blockIdx.x * 256 + threadIdx.x;
    s[threadIdx.x] = (i < nNodes) ? deg[i] : 0;
    __syncthreads();
    for (int o = 128; o > 0; o >>= 1) {
        if (threadIdx.x < o) s[threadIdx.x] += s[threadIdx.x + o];
        __syncthreads();
    }
    if (threadIdx.x == 0) bsum[blockIdx.x] = s[0];
}

// ------------------------------------- scan: single-block exclusive (nb<=1024)
__global__ void scan_block(int* __restrict__ bsum, int nb) {
    __shared__ int s[1024];
    int t = threadIdx.x;
    s[t] = (t < nb) ? bsum[t] : 0;
    __syncthreads();
    for (int o = 1; o < 1024; o <<= 1) {
        int v = (t >= o) ? s[t - o] : 0;
        __syncthreads();
        s[t] += v;
        __syncthreads();
    }
    int ex = (t > 0) ? s[t - 1] : 0;
    if (t < nb) bsum[t] = ex;
}

// ------------------- scan: per-element exclusive + offset -> rowstart, cursor
__global__ void scan_final(const int* __restrict__ deg, const int* __restrict__ boff,
                           int* __restrict__ rowstart, int* __restrict__ cursor,
                           int nNodes) {
    __shared__ int s[256];
    int i = blockIdx.x * 256 + threadIdx.x;
    int v = (i < nNodes) ? deg[i] : 0;
    s[threadIdx.x] = v;
    __syncthreads();
    for (int o = 1; o < 256; o <<= 1) {
        int u = (threadIdx.x >= o) ? s[threadIdx.x - o] : 0;
        __syncthreads();
        s[threadIdx.x] += u;
        __syncthreads();
    }
    int ex = boff[blockIdx.x] + ((threadIdx.x > 0) ? s[threadIdx.x - 1] : 0);
    if (i < nNodes) {
        rowstart[i] = ex;
        cursor[i]   = ex;
        if (i == nNodes - 1) rowstart[nNodes] = ex + v;
    }
}

// ------------------------------------------------------ CSR edge placement
__global__ void csr_fill(const int* __restrict__ src, const int* __restrict__ dst,
                         int* __restrict__ cursor, int* __restrict__ csr,
                         int nEdges) {
    int e = blockIdx.x * blockDim.x + threadIdx.x;
    if (e >= nEdges) return;
    int pos = atomicAdd(&cursor[dst[e]], 1);
    csr[pos] = src[e];
}

// ------------- gather v2: agg[node,:] = mean of neighbor rows (wave/node)
// 4 sub-groups x 16 lanes; sub-group r handles neighbor kb+r via DIRECT csr
// read (broadcast within group). No shuffles. Uniform wave trip count.
__global__ void gather_mean64_v2(const float* __restrict__ x,
                                 const int* __restrict__ rowstart,
                                 const int* __restrict__ csr,
                                 float* __restrict__ agg, int nNodes) {
    __shared__ float4 red[4][4][17];
    int wave = threadIdx.x >> 6, lane = threadIdx.x & 63;
    int node = blockIdx.x * 4 + wave;
    int r = lane >> 4, q = lane & 15;
    int beg = 0, end = 0;
    if (node < nNodes) { beg = rowstart[node]; end = rowstart[node + 1]; }
    const float4* x4 = (const float4*)x;
    float4 acc = make_float4(0.f, 0.f, 0.f, 0.f);
    for (int kb = beg; kb < end; kb += 4) {   // wave-uniform trip count
        int k = kb + r;
        if (k < end) {
            int s = csr[k];                    // same addr across 16 lanes
            float4 v = x4[(size_t)s * 16 + q]; // 4 rows / wave-iteration
            acc.x += v.x; acc.y += v.y; acc.z += v.z; acc.w += v.w;
        }
    }
    red[wave][r][q] = acc;
    __syncthreads();                           // block-uniform point
    if (lane < 16 && node < nNodes) {
        float4 a = red[wave][0][lane];
        float4 b = red[wave][1][lane];
        float4 c = red[wave][2][lane];
        float4 d = red[wave][3][lane];
        float inv = 1.0f / fmaxf((float)(end - beg), 1.0f);
        float4 o;
        o.x = (a.x + b.x + c.x + d.x) * inv;
        o.y = (a.y + b.y + c.y + d.y) * inv;
        o.z = (a.z + b.z + c.z + d.z) * inv;
        o.w = (a.w + b.w + c.w + d.w) * inv;
        ((float4*)agg)[(size_t)node * 16 + lane] = o;
    }
}

// ---------------- layer1 in-place: agg = relu(agg @ W1 + b1)  (4 nodes/block)
__global__ void layer1_inplace(float* __restrict__ agg, const float* __restrict__ W1,
                               const float* __restrict__ b1, int nNodes) {
    __shared__ float xs[4][F];
    int g = threadIdx.x >> 6, t = threadIdx.x & 63;
    int node = blockIdx.x * 4 + g;
    if (node < nNodes) xs[g][t] = agg[(size_t)node * F + t];
    __syncthreads();
    if (node >= nNodes) return;
    float acc = b1[t];
#pragma unroll
    for (int k = 0; k < F; ++k) acc = fmaf(xs[g][k], W1[k * F + t], acc);
    agg[(size_t)node * F + t] = fmaxf(acc, 0.0f);   // safe: row staged above
}

// -------------------------------------------------------- t2 = h @ W2
__global__ void mm2(const float* __restrict__ h, const float* __restrict__ W,
                    float* __restrict__ y, int nNodes) {
    __shared__ float ys[16][F + 1];
    int nodeBase = blockIdx.x * 16;
    for (int i = threadIdx.x; i < 16 * F; i += 256) {
        int n = i >> 6, k = i & 63;
        int node = nodeBase + n;
        ys[n][k] = (node < nNodes) ? h[(size_t)node * F + k] : 0.0f;
    }
    __syncthreads();
    int n = threadIdx.x >> 4, c = threadIdx.x & 15;
    int node = nodeBase + n;
    if (node >= nNodes) return;
    float acc = 0.0f;
#pragma unroll
    for (int k = 0; k < F; ++k) acc = fmaf(ys[n][k], W[k * C + c], acc);
    y[(size_t)node * C + c] = acc;
}

// ---------- gather16: out = mean_agg(t2) + b2 (wave/node, shuffle-free)
__global__ void gather16(const float* __restrict__ t2,
                         const int* __restrict__ rowstart,
                         const int* __restrict__ csr,
                         const float* __restrict__ b2,
                         float* __restrict__ out, int nNodes) {
    __shared__ float red[4][4][17];
    int wave = threadIdx.x >> 6, lane = threadIdx.x & 63;
    int node = blockIdx.x * 4 + wave;
    int r = lane >> 4, c = lane & 15;
    int beg = 0, end = 0;
    if (node < nNodes) { beg = rowstart[node]; end = rowstart[node + 1]; }
    float acc = 0.0f;
    for (int kb = beg; kb < end; kb += 4) {   // wave-uniform trip count
        int k = kb + r;
        if (k < end) {
            int s = csr[k];                    // broadcast within 16-lane group
            acc += t2[(size_t)s * C + c];      // 64B coalesced per group
        }
    }
    red[wave][r][c] = acc;
    __syncthreads();                           // block-uniform point
    if (lane < 16 && node < nNodes) {
        float sum = red[wave][0][lane] + red[wave][1][lane]
                  + red[wave][2][lane] + red[wave][3][lane];
        float d = fmaxf((float)(end - beg), 1.0f);
        out[(size_t)node * C + lane] = sum / d + b2[lane];
    }
}

// ---------------------------------------------------------------- launch
extern "C" void kernel_launch(void* const* d_in, const int* in_sizes, int n_in,
                              void* d_out, int out_size, void* d_ws, size_t ws_size,
                              hipStream_t stream) {
    const float* features = (const float*)d_in[0];
    const int*   src      = (const int*)d_in[1];
    const int*   dst      = (const int*)d_in[2];
    const float* W1       = (const float*)d_in[3];
    const float* b1       = (const float*)d_in[4];
    const float* W2       = (const float*)d_in[5];
    const float* b2       = (const float*)d_in[6];
    float*       out      = (float*)d_out;

    const int nNodes = in_sizes[0] / F;
    const int nEdges = in_sizes[1];
    const int NB = (nNodes + 255) / 256;   // 391 <= 1024

    // ---- workspace carve-up (peak 39.6 MiB; round-4 proved >=46 MiB works)
    char* ws = (char*)d_ws;
    auto align = [](size_t x) { return (x + 255) / 256 * 256; };
    int* deg      = (int*)ws;      ws += align((size_t)nNodes * 4);
    int* rowstart = (int*)ws;      ws += align((size_t)(nNodes + 1) * 4);
    int* cursor   = (int*)ws;      ws += align((size_t)nNodes * 4);
    int* bsum     = (int*)ws;      ws += align((size_t)NB * 4);
    int* csr      = (int*)ws;      ws += align((size_t)nEdges * 4);
    float* agg    = (float*)ws;    ws += align((size_t)nNodes * F * 4);   // also h
    float* t2     = (float*)ws;    ws += align((size_t)nNodes * C * 4);

    hipMemsetAsync(deg, 0, (size_t)nNodes * sizeof(int), stream);

    // ---- CSR build (dst-sorted adjacency) — byte-identical to round 4
    deg_count<<<(nEdges + 255) / 256, 256, 0, stream>>>(dst, deg, nEdges);
    scan_part<<<NB, 256, 0, stream>>>(deg, bsum, nNodes);
    scan_block<<<1, 1024, 0, stream>>>(bsum, NB);
    scan_final<<<NB, 256, 0, stream>>>(deg, bsum, rowstart, cursor, nNodes);
    csr_fill<<<(nEdges + 255) / 256, 256, 0, stream>>>(src, dst, cursor, csr, nEdges);

    // ---- layer 1: agg = mean_agg(features); agg = relu(agg@W1 + b1) in-place
    gather_mean64_v2<<<(nNodes + 3) / 4, 256, 0, stream>>>(features, rowstart, csr, agg, nNodes);
    layer1_inplace<<<(nNodes + 3) / 4, 256, 0, stream>>>(agg, W1, b1, nNodes);

    // ---- layer 2 (W2 pushed through mean-agg): t2 = h@W2; out = mean_agg(t2)+b2
    mm2<<<(nNodes + 15) / 16, 256, 0, stream>>>(agg, W2, t2, nNodes);
    gather16<<<(nNodes + 3) / 4, 256, 0, stream>>>(t2, rowstart, csr, b2, out, nNodes);
}

// Round 6
// 260.521 us; speedup vs baseline: 3.3403x; 1.5378x over previous
//
#include <hip/hip_runtime.h>

static constexpr int F = 64;   // IN_FEATS == HIDDEN
static constexpr int C = 16;   // NUM_CLASSES
static constexpr int EPB = 8192;        // edges per block (hist/partition)
static constexpr int BSH = 9;           // bucket shift: 512 nodes/bucket

// -------------------------------------------------- per-block bucket histogram
__global__ void hist_k(const int* __restrict__ dst, int* __restrict__ bucketCount,
                       int nEdges) {
    __shared__ int h[256];
    int t = threadIdx.x;
    h[t] = 0;
    __syncthreads();
    int e0 = blockIdx.x * EPB;
    for (int i = 0; i < EPB / 256; ++i) {
        int e = e0 + i * 256 + t;
        if (e < nEdges) atomicAdd(&h[dst[e] >> BSH], 1);
    }
    __syncthreads();
    if (h[t]) atomicAdd(&bucketCount[t], h[t]);
}

// ------------------------------- exclusive scan of 256 bucket counts (1 block)
__global__ void bucket_scan(const int* __restrict__ bucketCount,
                            int* __restrict__ bucketStart,
                            int* __restrict__ bucketCursor) {
    __shared__ int s[256];
    int t = threadIdx.x;
    s[t] = bucketCount[t];
    __syncthreads();
    for (int o = 1; o < 256; o <<= 1) {
        int v = (t >= o) ? s[t - o] : 0;
        __syncthreads();
        s[t] += v;
        __syncthreads();
    }
    int ex = (t > 0) ? s[t - 1] : 0;
    bucketStart[t]  = ex;
    bucketCursor[t] = ex;
    if (t == 255) bucketStart[256] = s[255];
}

// -------------------- partition edges into bucket-contiguous (dst,src) pairs
__global__ void partition(const int* __restrict__ src, const int* __restrict__ dst,
                          int* __restrict__ bucketCursor, uint2* __restrict__ pairs,
                          int nEdges) {
    __shared__ int h[256];
    __shared__ int base[256];
    __shared__ int rank[256];
    int t = threadIdx.x;
    h[t] = 0; rank[t] = 0;
    __syncthreads();
    int e0 = blockIdx.x * EPB;
    for (int i = 0; i < EPB / 256; ++i) {
        int e = e0 + i * 256 + t;
        if (e < nEdges) atomicAdd(&h[dst[e] >> BSH], 1);
    }
    __syncthreads();
    base[t] = h[t] ? atomicAdd(&bucketCursor[t], h[t]) : 0;  // contiguous slice
    __syncthreads();
    for (int i = 0; i < EPB / 256; ++i) {
        int e = e0 + i * 256 + t;
        if (e < nEdges) {
            int d = dst[e];
            int b = d >> BSH;
            int r = atomicAdd(&rank[b], 1);
            pairs[base[b] + r] = make_uint2((unsigned)d, (unsigned)src[e]);
        }
    }
}

// ------- per-bucket: degrees -> local scan -> rowstart + csr (single writer)
__global__ void bucket_csr(const uint2* __restrict__ pairs,
                           const int* __restrict__ bucketStart,
                           int* __restrict__ rowstart, int* __restrict__ csr,
                           int nNodes, int nEdges) {
    __shared__ int cnt[512];
    __shared__ int s[512];
    __shared__ int cur[512];
    int t = threadIdx.x;
    int b = blockIdx.x;
    int nodeBase = b << BSH;
    int pBeg = bucketStart[b], pEnd = bucketStart[b + 1];
    cnt[t] = 0;
    __syncthreads();
    for (int i = pBeg + t; i < pEnd; i += 512)
        atomicAdd(&cnt[pairs[i].x - nodeBase], 1);
    __syncthreads();
    s[t] = cnt[t];
    __syncthreads();
    for (int o = 1; o < 512; o <<= 1) {
        int v = (t >= o) ? s[t - o] : 0;
        __syncthreads();
        s[t] += v;
        __syncthreads();
    }
    int rs = pBeg + ((t > 0) ? s[t - 1] : 0);
    int node = nodeBase + t;
    if (node < nNodes) rowstart[node] = rs;
    cur[t] = rs;
    __syncthreads();
    for (int i = pBeg + t; i < pEnd; i += 512) {
        uint2 p = pairs[i];
        int pos = atomicAdd(&cur[p.x - nodeBase], 1);
        csr[pos] = (int)p.y;
    }
    if (b == 0 && t == 0) rowstart[nNodes] = nEdges;
}

// ------------- gather v2: agg[node,:] = mean of neighbor rows (wave/node)
// (byte-identical to round 5 — proven)
__global__ void gather_mean64_v2(const float* __restrict__ x,
                                 const int* __restrict__ rowstart,
                                 const int* __restrict__ csr,
                                 float* __restrict__ agg, int nNodes) {
    __shared__ float4 red[4][4][17];
    int wave = threadIdx.x >> 6, lane = threadIdx.x & 63;
    int node = blockIdx.x * 4 + wave;
    int r = lane >> 4, q = lane & 15;
    int beg = 0, end = 0;
    if (node < nNodes) { beg = rowstart[node]; end = rowstart[node + 1]; }
    const float4* x4 = (const float4*)x;
    float4 acc = make_float4(0.f, 0.f, 0.f, 0.f);
    for (int kb = beg; kb < end; kb += 4) {   // wave-uniform trip count
        int k = kb + r;
        if (k < end) {
            int s = csr[k];                    // same addr across 16 lanes
            float4 v = x4[(size_t)s * 16 + q]; // 4 rows / wave-iteration
            acc.x += v.x; acc.y += v.y; acc.z += v.z; acc.w += v.w;
        }
    }
    red[wave][r][q] = acc;
    __syncthreads();                           // block-uniform point
    if (lane < 16 && node < nNodes) {
        float4 a = red[wave][0][lane];
        float4 b = red[wave][1][lane];
        float4 c = red[wave][2][lane];
        float4 d = red[wave][3][lane];
        float inv = 1.0f / fmaxf((float)(end - beg), 1.0f);
        float4 o;
        o.x = (a.x + b.x + c.x + d.x) * inv;
        o.y = (a.y + b.y + c.y + d.y) * inv;
        o.z = (a.z + b.z + c.z + d.z) * inv;
        o.w = (a.w + b.w + c.w + d.w) * inv;
        ((float4*)agg)[(size_t)node * 16 + lane] = o;
    }
}

// ---------------- layer1 in-place: agg = relu(agg @ W1 + b1)  (4 nodes/block)
__global__ void layer1_inplace(float* __restrict__ agg, const float* __restrict__ W1,
                               const float* __restrict__ b1, int nNodes) {
    __shared__ float xs[4][F];
    int g = threadIdx.x >> 6, t = threadIdx.x & 63;
    int node = blockIdx.x * 4 + g;
    if (node < nNodes) xs[g][t] = agg[(size_t)node * F + t];
    __syncthreads();
    if (node >= nNodes) return;
    float acc = b1[t];
#pragma unroll
    for (int k = 0; k < F; ++k) acc = fmaf(xs[g][k], W1[k * F + t], acc);
    agg[(size_t)node * F + t] = fmaxf(acc, 0.0f);   // safe: row staged above
}

// -------------------------------------------------------- t2 = h @ W2
__global__ void mm2(const float* __restrict__ h, const float* __restrict__ W,
                    float* __restrict__ y, int nNodes) {
    __shared__ float ys[16][F + 1];
    int nodeBase = blockIdx.x * 16;
    for (int i = threadIdx.x; i < 16 * F; i += 256) {
        int n = i >> 6, k = i & 63;
        int node = nodeBase + n;
        ys[n][k] = (node < nNodes) ? h[(size_t)node * F + k] : 0.0f;
    }
    __syncthreads();
    int n = threadIdx.x >> 4, c = threadIdx.x & 15;
    int node = nodeBase + n;
    if (node >= nNodes) return;
    float acc = 0.0f;
#pragma unroll
    for (int k = 0; k < F; ++k) acc = fmaf(ys[n][k], W[k * C + c], acc);
    y[(size_t)node * C + c] = acc;
}

// ---------- gather16: out = mean_agg(t2) + b2 (wave/node, shuffle-free)
// (byte-identical to round 5 — proven)
__global__ void gather16(const float* __restrict__ t2,
                         const int* __restrict__ rowstart,
                         const int* __restrict__ csr,
                         const float* __restrict__ b2,
                         float* __restrict__ out, int nNodes) {
    __shared__ float red[4][4][17];
    int wave = threadIdx.x >> 6, lane = threadIdx.x & 63;
    int node = blockIdx.x * 4 + wave;
    int r = lane >> 4, c = lane & 15;
    int beg = 0, end = 0;
    if (node < nNodes) { beg = rowstart[node]; end = rowstart[node + 1]; }
    float acc = 0.0f;
    for (int kb = beg; kb < end; kb += 4) {   // wave-uniform trip count
        int k = kb + r;
        if (k < end) {
            int s = csr[k];                    // broadcast within 16-lane group
            acc += t2[(size_t)s * C + c];      // 64B coalesced per group
        }
    }
    red[wave][r][c] = acc;
    __syncthreads();                           // block-uniform point
    if (lane < 16 && node < nNodes) {
        float sum = red[wave][0][lane] + red[wave][1][lane]
                  + red[wave][2][lane] + red[wave][3][lane];
        float d = fmaxf((float)(end - beg), 1.0f);
        out[(size_t)node * C + lane] = sum / d + b2[lane];
    }
}

// ---------------------------------------------------------------- launch
extern "C" void kernel_launch(void* const* d_in, const int* in_sizes, int n_in,
                              void* d_out, int out_size, void* d_ws, size_t ws_size,
                              hipStream_t stream) {
    const float* features = (const float*)d_in[0];
    const int*   src      = (const int*)d_in[1];
    const int*   dst      = (const int*)d_in[2];
    const float* W1       = (const float*)d_in[3];
    const float* b1       = (const float*)d_in[4];
    const float* W2       = (const float*)d_in[5];
    const float* b2       = (const float*)d_in[6];
    float*       out      = (float*)d_out;

    const int nNodes = in_sizes[0] / F;           // 100000
    const int nEdges = in_sizes[1];               // 1600000
    const int NBUCK = (nNodes + 511) >> BSH;      // 196 (<= 256)
    const int NBLK  = (nEdges + EPB - 1) / EPB;   // 196

    // ---- workspace carve-up (peak ~38.9 MiB; round-4 proved >=46 MiB works)
    char* ws = (char*)d_ws;
    auto align = [](size_t x) { return (x + 255) / 256 * 256; };
    int* bucketCount  = (int*)ws;  ws += align(256 * 4);
    int* bucketStart  = (int*)ws;  ws += align(257 * 4);
    int* bucketCursor = (int*)ws;  ws += align(256 * 4);
    int* rowstart     = (int*)ws;  ws += align((size_t)(nNodes + 1) * 4);
    int* csr          = (int*)ws;  ws += align((size_t)nEdges * 4);
    float* agg        = (float*)ws; ws += align((size_t)nNodes * F * 4);  // also h
    float* t2         = (float*)ws; ws += align((size_t)nNodes * C * 4);
    uint2* pairs      = (uint2*)agg;   // 12.8 MB, dead before agg is written

    hipMemsetAsync(bucketCount, 0, 256 * sizeof(int), stream);

    // ---- CSR build: bucketed, single-writer lines, no global deg/scan
    hist_k<<<NBLK, 256, 0, stream>>>(dst, bucketCount, nEdges);
    bucket_scan<<<1, 256, 0, stream>>>(bucketCount, bucketStart, bucketCursor);
    partition<<<NBLK, 256, 0, stream>>>(src, dst, bucketCursor, pairs, nEdges);
    bucket_csr<<<NBUCK, 512, 0, stream>>>(pairs, bucketStart, rowstart, csr,
                                          nNodes, nEdges);

    // ---- layer 1: agg = mean_agg(features); agg = relu(agg@W1 + b1) in-place
    gather_mean64_v2<<<(nNodes + 3) / 4, 256, 0, stream>>>(features, rowstart, csr, agg, nNodes);
    layer1_inplace<<<(nNodes + 3) / 4, 256, 0, stream>>>(agg, W1, b1, nNodes);

    // ---- layer 2 (W2 pushed through mean-agg): t2 = h@W2; out = mean_agg(t2)+b2
    mm2<<<(nNodes + 15) / 16, 256, 0, stream>>>(agg, W2, t2, nNodes);
    gather16<<<(nNodes + 3) / 4, 256, 0, stream>>>(t2, rowstart, csr, b2, out, nNodes);
}

// Round 7
// 255.940 us; speedup vs baseline: 3.4001x; 1.0179x over previous
//
#include <hip/hip_runtime.h>

static constexpr int F = 64;      // IN_FEATS == HIDDEN
static constexpr int C = 16;      // NUM_CLASSES
static constexpr int EPB = 8192;  // edges per block (hist/partition)
static constexpr int BSH = 9;     // bucket shift: 512 nodes/bucket
static constexpr int SRCB = 17;   // src id bits (nNodes <= 131072)

// -------------------------------------------------- per-block bucket histogram
__global__ void hist_k(const int* __restrict__ dst, int* __restrict__ bucketCount,
                       int nEdges) {
    __shared__ int h[256];
    int t = threadIdx.x;
    h[t] = 0;
    __syncthreads();
    int e0 = blockIdx.x * EPB;
    for (int i = 0; i < EPB / 256; ++i) {
        int e = e0 + i * 256 + t;
        if (e < nEdges) atomicAdd(&h[dst[e] >> BSH], 1);
    }
    __syncthreads();
    if (h[t]) atomicAdd(&bucketCount[t], h[t]);
}

// ------------------------------- exclusive scan of 256 bucket counts (1 block)
__global__ void bucket_scan(const int* __restrict__ bucketCount,
                            int* __restrict__ bucketStart,
                            int* __restrict__ bucketCursor) {
    __shared__ int s[256];
    int t = threadIdx.x;
    s[t] = bucketCount[t];
    __syncthreads();
    for (int o = 1; o < 256; o <<= 1) {
        int v = (t >= o) ? s[t - o] : 0;
        __syncthreads();
        s[t] += v;
        __syncthreads();
    }
    int ex = (t > 0) ? s[t - 1] : 0;
    bucketStart[t]  = ex;
    bucketCursor[t] = ex;
    if (t == 255) bucketStart[256] = s[255];
}

// ------------- partition edges into bucket-contiguous packed (dloc,src) words
__global__ void partition(const int* __restrict__ src, const int* __restrict__ dst,
                          int* __restrict__ bucketCursor, unsigned* __restrict__ pairs,
                          int nEdges) {
    __shared__ int h[256];
    __shared__ int base[256];
    __shared__ int rank[256];
    int t = threadIdx.x;
    h[t] = 0; rank[t] = 0;
    __syncthreads();
    int e0 = blockIdx.x * EPB;
    for (int i = 0; i < EPB / 256; ++i) {
        int e = e0 + i * 256 + t;
        if (e < nEdges) atomicAdd(&h[dst[e] >> BSH], 1);
    }
    __syncthreads();
    base[t] = h[t] ? atomicAdd(&bucketCursor[t], h[t]) : 0;  // contiguous slice
    __syncthreads();
    for (int i = 0; i < EPB / 256; ++i) {
        int e = e0 + i * 256 + t;
        if (e < nEdges) {
            int d = dst[e];
            int b = d >> BSH;
            int r = atomicAdd(&rank[b], 1);
            pairs[base[b] + r] =
                ((unsigned)(d & ((1 << BSH) - 1)) << SRCB) | (unsigned)src[e];
        }
    }
}

// ------- per-bucket: degrees -> local scan -> rowstart + csr (single writer)
__global__ void bucket_csr(const unsigned* __restrict__ pairs,
                           const int* __restrict__ bucketStart,
                           int* __restrict__ rowstart, int* __restrict__ csr,
                           int nNodes, int nEdges) {
    __shared__ int cnt[512];
    __shared__ int s[512];
    __shared__ int cur[512];
    int t = threadIdx.x;
    int b = blockIdx.x;
    int nodeBase = b << BSH;
    int pBeg = bucketStart[b], pEnd = bucketStart[b + 1];
    cnt[t] = 0;
    __syncthreads();
    for (int i = pBeg + t; i < pEnd; i += 512)
        atomicAdd(&cnt[pairs[i] >> SRCB], 1);
    __syncthreads();
    s[t] = cnt[t];
    __syncthreads();
    for (int o = 1; o < 512; o <<= 1) {
        int v = (t >= o) ? s[t - o] : 0;
        __syncthreads();
        s[t] += v;
        __syncthreads();
    }
    int rs = pBeg + ((t > 0) ? s[t - 1] : 0);
    int node = nodeBase + t;
    if (node < nNodes) rowstart[node] = rs;
    cur[t] = rs;
    __syncthreads();
    for (int i = pBeg + t; i < pEnd; i += 512) {
        unsigned p = pairs[i];
        int pos = atomicAdd(&cur[p >> SRCB], 1);
        csr[pos] = (int)(p & ((1u << SRCB) - 1));
    }
    if (b == 0 && t == 0) rowstart[nNodes] = nEdges;
}

// ---- fused layer 1 + pushdown MM: t2[node,:] = relu(mean_agg(x)@W1+b1)@W2
// Phase 1 (gather) is byte-identical to the proven gather_mean64_v2 loop;
// agg row stays in LDS, h and t2 computed in-block. Only t2 hits global.
__global__ void fused_l1(const float* __restrict__ x,
                         const int* __restrict__ rowstart,
                         const int* __restrict__ csr,
                         const float* __restrict__ W1,
                         const float* __restrict__ b1,
                         const float* __restrict__ W2,
                         float* __restrict__ t2, int nNodes) {
    __shared__ float4 red[4][4][17];
    __shared__ float xs[4][F];
    __shared__ float hs[4][F];
    int wave = threadIdx.x >> 6, lane = threadIdx.x & 63;
    int node = blockIdx.x * 4 + wave;
    int r = lane >> 4, q = lane & 15;
    int beg = 0, end = 0;
    if (node < nNodes) { beg = rowstart[node]; end = rowstart[node + 1]; }
    const float4* x4 = (const float4*)x;
    float4 acc = make_float4(0.f, 0.f, 0.f, 0.f);
    for (int kb = beg; kb < end; kb += 4) {   // wave-uniform trip count
        int k = kb + r;
        if (k < end) {
            int s = csr[k];                    // same addr across 16 lanes
            float4 v = x4[(size_t)s * 16 + q]; // 4 rows / wave-iteration
            acc.x += v.x; acc.y += v.y; acc.z += v.z; acc.w += v.w;
        }
    }
    red[wave][r][q] = acc;
    __syncthreads();                           // block-uniform point
    if (lane < 16) {
        float4 a = red[wave][0][lane];
        float4 b = red[wave][1][lane];
        float4 c = red[wave][2][lane];
        float4 d = red[wave][3][lane];
        float inv = 1.0f / fmaxf((float)(end - beg), 1.0f);
        float4 o;
        o.x = (a.x + b.x + c.x + d.x) * inv;
        o.y = (a.y + b.y + c.y + d.y) * inv;
        o.z = (a.z + b.z + c.z + d.z) * inv;
        o.w = (a.w + b.w + c.w + d.w) * inv;
        ((float4*)xs[wave])[lane] = o;         // agg row -> LDS (0 for dead node)
    }
    __syncthreads();                           // block-uniform point
    // h[t] = relu(agg @ W1 + b1)  — all 64 lanes, broadcast LDS reads
    float hacc = b1[lane];
#pragma unroll
    for (int k = 0; k < F; ++k) hacc = fmaf(xs[wave][k], W1[k * F + lane], hacc);
    hs[wave][lane] = fmaxf(hacc, 0.0f);
    __syncthreads();                           // block-uniform point
    // t2[c] = h @ W2 — 16 lanes, 64B coalesced store per node
    if (lane < C && node < nNodes) {
        float oacc = 0.0f;
#pragma unroll
        for (int k = 0; k < F; ++k) oacc = fmaf(hs[wave][k], W2[k * C + lane], oacc);
        t2[(size_t)node * C + lane] = oacc;
    }
}

// ---------- gather16: out = mean_agg(t2) + b2 (wave/node, shuffle-free)
// (byte-identical to rounds 5/6 — proven)
__global__ void gather16(const float* __restrict__ t2,
                         const int* __restrict__ rowstart,
                         const int* __restrict__ csr,
                         const float* __restrict__ b2,
                         float* __restrict__ out, int nNodes) {
    __shared__ float red[4][4][17];
    int wave = threadIdx.x >> 6, lane = threadIdx.x & 63;
    int node = blockIdx.x * 4 + wave;
    int r = lane >> 4, c = lane & 15;
    int beg = 0, end = 0;
    if (node < nNodes) { beg = rowstart[node]; end = rowstart[node + 1]; }
    float acc = 0.0f;
    for (int kb = beg; kb < end; kb += 4) {   // wave-uniform trip count
        int k = kb + r;
        if (k < end) {
            int s = csr[k];                    // broadcast within 16-lane group
            acc += t2[(size_t)s * C + c];      // 64B coalesced per group
        }
    }
    red[wave][r][c] = acc;
    __syncthreads();                           // block-uniform point
    if (lane < 16 && node < nNodes) {
        float sum = red[wave][0][lane] + red[wave][1][lane]
                  + red[wave][2][lane] + red[wave][3][lane];
        float d = fmaxf((float)(end - beg), 1.0f);
        out[(size_t)node * C + lane] = sum / d + b2[lane];
    }
}

// ---------------------------------------------------------------- launch
extern "C" void kernel_launch(void* const* d_in, const int* in_sizes, int n_in,
                              void* d_out, int out_size, void* d_ws, size_t ws_size,
                              hipStream_t stream) {
    const float* features = (const float*)d_in[0];
    const int*   src      = (const int*)d_in[1];
    const int*   dst      = (const int*)d_in[2];
    const float* W1       = (const float*)d_in[3];
    const float* b1       = (const float*)d_in[4];
    const float* W2       = (const float*)d_in[5];
    const float* b2       = (const float*)d_in[6];
    float*       out      = (float*)d_out;

    const int nNodes = in_sizes[0] / F;           // 100000
    const int nEdges = in_sizes[1];               // 1600000
    const int NBUCK = (nNodes + 511) >> BSH;      // 196 (<= 256)
    const int NBLK  = (nEdges + EPB - 1) / EPB;   // 196

    // ---- workspace carve-up (peak ~20 MiB; round-4 proved >=46 MiB works)
    char* ws = (char*)d_ws;
    auto align = [](size_t x) { return (x + 255) / 256 * 256; };
    int* bucketCount  = (int*)ws;      ws += align(256 * 4);
    int* bucketStart  = (int*)ws;      ws += align(257 * 4);
    int* bucketCursor = (int*)ws;      ws += align(256 * 4);
    int* rowstart     = (int*)ws;      ws += align((size_t)(nNodes + 1) * 4);
    int* csr          = (int*)ws;      ws += align((size_t)nEdges * 4);
    unsigned* pairs   = (unsigned*)ws; ws += align((size_t)nEdges * 4);
    float* t2         = (float*)ws;    ws += align((size_t)nNodes * C * 4);

    hipMemsetAsync(bucketCount, 0, 256 * sizeof(int), stream);

    // ---- CSR build: bucketed, single-writer lines, packed u32 pairs
    hist_k<<<NBLK, 256, 0, stream>>>(dst, bucketCount, nEdges);
    bucket_scan<<<1, 256, 0, stream>>>(bucketCount, bucketStart, bucketCursor);
    partition<<<NBLK, 256, 0, stream>>>(src, dst, bucketCursor, pairs, nEdges);
    bucket_csr<<<NBUCK, 512, 0, stream>>>(pairs, bucketStart, rowstart, csr,
                                          nNodes, nEdges);

    // ---- fused layer 1 + W2 pushdown: t2 = relu(mean_agg(x)@W1+b1)@W2
    fused_l1<<<(nNodes + 3) / 4, 256, 0, stream>>>(features, rowstart, csr,
                                                   W1, b1, W2, t2, nNodes);

    // ---- layer 2 aggregation: out = mean_agg(t2) + b2
    gather16<<<(nNodes + 3) / 4, 256, 0, stream>>>(t2, rowstart, csr, b2, out, nNodes);
}

// Round 8
// 249.341 us; speedup vs baseline: 3.4901x; 1.0265x over previous
//
#include <hip/hip_runtime.h>
#include <hip/hip_fp16.h>

static constexpr int F = 64;      // IN_FEATS == HIDDEN
static constexpr int C = 16;      // NUM_CLASSES
static constexpr int EPB = 8192;  // edges per block (hist/partition)
static constexpr int BSH = 9;     // bucket shift: 512 nodes/bucket
static constexpr int SRCB = 17;   // src id bits (nNodes <= 131072)

// -------------------------------------------- features fp32 -> fp16 (packed)
__global__ void to_half(const float* __restrict__ x, __half* __restrict__ xh,
                        int n4) {
    int i = blockIdx.x * blockDim.x + threadIdx.x;
    if (i >= n4) return;
    float4 v = ((const float4*)x)[i];
    __half2 p0 = __floats2half2_rn(v.x, v.y);
    __half2 p1 = __floats2half2_rn(v.z, v.w);
    uint2 o;
    o.x = *reinterpret_cast<unsigned*>(&p0);
    o.y = *reinterpret_cast<unsigned*>(&p1);
    ((uint2*)xh)[i] = o;
}

// ---------------- per-block bucket histogram (also saved for partition reuse)
__global__ void hist_k(const int* __restrict__ dst, int* __restrict__ bucketCount,
                       int* __restrict__ blockHist, int nEdges) {
    __shared__ int h[256];
    int t = threadIdx.x;
    h[t] = 0;
    __syncthreads();
    int e0 = blockIdx.x * EPB;
    for (int i = 0; i < EPB / 256; ++i) {
        int e = e0 + i * 256 + t;
        if (e < nEdges) atomicAdd(&h[dst[e] >> BSH], 1);
    }
    __syncthreads();
    blockHist[blockIdx.x * 256 + t] = h[t];
    if (h[t]) atomicAdd(&bucketCount[t], h[t]);
}

// ------------------------------- exclusive scan of 256 bucket counts (1 block)
__global__ void bucket_scan(const int* __restrict__ bucketCount,
                            int* __restrict__ bucketStart,
                            int* __restrict__ bucketCursor) {
    __shared__ int s[256];
    int t = threadIdx.x;
    s[t] = bucketCount[t];
    __syncthreads();
    for (int o = 1; o < 256; o <<= 1) {
        int v = (t >= o) ? s[t - o] : 0;
        __syncthreads();
        s[t] += v;
        __syncthreads();
    }
    int ex = (t > 0) ? s[t - 1] : 0;
    bucketStart[t]  = ex;
    bucketCursor[t] = ex;
    if (t == 255) bucketStart[256] = s[255];
}

// ------------- partition edges into bucket-contiguous packed (dloc,src) words
// (histogram phase replaced by blockHist reload)
__global__ void partition(const int* __restrict__ src, const int* __restrict__ dst,
                          const int* __restrict__ blockHist,
                          int* __restrict__ bucketCursor, unsigned* __restrict__ pairs,
                          int nEdges) {
    __shared__ int base[256];
    __shared__ int rank[256];
    int t = threadIdx.x;
    rank[t] = 0;
    int c = blockHist[blockIdx.x * 256 + t];
    base[t] = c ? atomicAdd(&bucketCursor[t], c) : 0;  // contiguous slice
    __syncthreads();
    int e0 = blockIdx.x * EPB;
    for (int i = 0; i < EPB / 256; ++i) {
        int e = e0 + i * 256 + t;
        if (e < nEdges) {
            int d = dst[e];
            int b = d >> BSH;
            int r = atomicAdd(&rank[b], 1);
            pairs[base[b] + r] =
                ((unsigned)(d & ((1 << BSH) - 1)) << SRCB) | (unsigned)src[e];
        }
    }
}

// ------- per-bucket: degrees -> local scan -> rowstart + csr (single writer)
__global__ void bucket_csr(const unsigned* __restrict__ pairs,
                           const int* __restrict__ bucketStart,
                           int* __restrict__ rowstart, int* __restrict__ csr,
                           int nNodes, int nEdges) {
    __shared__ int cnt[512];
    __shared__ int s[512];
    __shared__ int cur[512];
    int t = threadIdx.x;
    int b = blockIdx.x;
    int nodeBase = b << BSH;
    int pBeg = bucketStart[b], pEnd = bucketStart[b + 1];
    cnt[t] = 0;
    __syncthreads();
    for (int i = pBeg + t; i < pEnd; i += 512)
        atomicAdd(&cnt[pairs[i] >> SRCB], 1);
    __syncthreads();
    s[t] = cnt[t];
    __syncthreads();
    for (int o = 1; o < 512; o <<= 1) {
        int v = (t >= o) ? s[t - o] : 0;
        __syncthreads();
        s[t] += v;
        __syncthreads();
    }
    int rs = pBeg + ((t > 0) ? s[t - 1] : 0);
    int node = nodeBase + t;
    if (node < nNodes) rowstart[node] = rs;
    cur[t] = rs;
    __syncthreads();
    for (int i = pBeg + t; i < pEnd; i += 512) {
        unsigned p = pairs[i];
        int pos = atomicAdd(&cur[p >> SRCB], 1);
        csr[pos] = (int)(p & ((1u << SRCB) - 1));
    }
    if (b == 0 && t == 0) rowstart[nNodes] = nEdges;
}

// ------- gather (fp16 rows): agg[node,:] = mean of neighbor rows (wave/node)
// structure byte-identical to proven gather_mean64_v2; row loads are uint2
__global__ void gather_h(const __half* __restrict__ xh,
                         const int* __restrict__ rowstart,
                         const int* __restrict__ csr,
                         float* __restrict__ agg, int nNodes) {
    __shared__ float4 red[4][4][17];
    int wave = threadIdx.x >> 6, lane = threadIdx.x & 63;
    int node = blockIdx.x * 4 + wave;
    int r = lane >> 4, q = lane & 15;
    int beg = 0, end = 0;
    if (node < nNodes) { beg = rowstart[node]; end = rowstart[node + 1]; }
    const uint2* x2 = (const uint2*)xh;
    float4 acc = make_float4(0.f, 0.f, 0.f, 0.f);
    for (int kb = beg; kb < end; kb += 4) {   // wave-uniform trip count
        int k = kb + r;
        if (k < end) {
            int s = csr[k];                    // same addr across 16 lanes
            uint2 u = x2[(size_t)s * 16 + q];  // 128B row / 16-lane group
            __half2 h0 = *reinterpret_cast<__half2*>(&u.x);
            __half2 h1 = *reinterpret_cast<__half2*>(&u.y);
            acc.x += __low2float(h0); acc.y += __high2float(h0);
            acc.z += __low2float(h1); acc.w += __high2float(h1);
        }
    }
    red[wave][r][q] = acc;
    __syncthreads();                           // block-uniform point
    if (lane < 16 && node < nNodes) {
        float4 a = red[wave][0][lane];
        float4 b = red[wave][1][lane];
        float4 c = red[wave][2][lane];
        float4 d = red[wave][3][lane];
        float inv = 1.0f / fmaxf((float)(end - beg), 1.0f);
        float4 o;
        o.x = (a.x + b.x + c.x + d.x) * inv;
        o.y = (a.y + b.y + c.y + d.y) * inv;
        o.z = (a.z + b.z + c.z + d.z) * inv;
        o.w = (a.w + b.w + c.w + d.w) * inv;
        ((float4*)agg)[(size_t)node * 16 + lane] = o;
    }
}

// ---------------- layer1 in-place: agg = relu(agg @ W1 + b1)  (4 nodes/block)
// (byte-identical to round 6 — proven)
__global__ void layer1_inplace(float* __restrict__ agg, const float* __restrict__ W1,
                               const float* __restrict__ b1, int nNodes) {
    __shared__ float xs[4][F];
    int g = threadIdx.x >> 6, t = threadIdx.x & 63;
    int node = blockIdx.x * 4 + g;
    if (node < nNodes) xs[g][t] = agg[(size_t)node * F + t];
    __syncthreads();
    if (node >= nNodes) return;
    float acc = b1[t];
#pragma unroll
    for (int k = 0; k < F; ++k) acc = fmaf(xs[g][k], W1[k * F + t], acc);
    agg[(size_t)node * F + t] = fmaxf(acc, 0.0f);   // safe: row staged above
}

// ------------------------------------------- t2 = h @ W2 (fp16 output rows)
__global__ void mm2h(const float* __restrict__ h, const float* __restrict__ W,
                     __half* __restrict__ y, int nNodes) {
    __shared__ float ys[16][F + 1];
    int nodeBase = blockIdx.x * 16;
    for (int i = threadIdx.x; i < 16 * F; i += 256) {
        int n = i >> 6, k = i & 63;
        int node = nodeBase + n;
        ys[n][k] = (node < nNodes) ? h[(size_t)node * F + k] : 0.0f;
    }
    __syncthreads();
    int n = threadIdx.x >> 4, c = threadIdx.x & 15;
    int node = nodeBase + n;
    if (node >= nNodes) return;
    float acc = 0.0f;
#pragma unroll
    for (int k = 0; k < F; ++k) acc = fmaf(ys[n][k], W[k * C + c], acc);
    y[(size_t)node * C + c] = __float2half_rn(acc);
}

// ---------- gather16h: out = mean_agg(t2) + b2 (wave/node, shuffle-free)
// structure byte-identical to proven gather16; t2 rows are fp16
__global__ void gather16h(const __half* __restrict__ t2,
                          const int* __restrict__ rowstart,
                          const int* __restrict__ csr,
                          const float* __restrict__ b2,
                          float* __restrict__ out, int nNodes) {
    __shared__ float red[4][4][17];
    int wave = threadIdx.x >> 6, lane = threadIdx.x & 63;
    int node = blockIdx.x * 4 + wave;
    int r = lane >> 4, c = lane & 15;
    int beg = 0, end = 0;
    if (node < nNodes) { beg = rowstart[node]; end = rowstart[node + 1]; }
    float acc = 0.0f;
    for (int kb = beg; kb < end; kb += 4) {   // wave-uniform trip count
        int k = kb + r;
        if (k < end) {
            int s = csr[k];                    // broadcast within 16-lane group
            acc += __half2float(t2[(size_t)s * C + c]);  // 32B per group
        }
    }
    red[wave][r][c] = acc;
    __syncthreads();                           // block-uniform point
    if (lane < 16 && node < nNodes) {
        float sum = red[wave][0][lane] + red[wave][1][lane]
                  + red[wave][2][lane] + red[wave][3][lane];
        float d = fmaxf((float)(end - beg), 1.0f);
        out[(size_t)node * C + lane] = sum / d + b2[lane];
    }
}

// ---------------------------------------------------------------- launch
extern "C" void kernel_launch(void* const* d_in, const int* in_sizes, int n_in,
                              void* d_out, int out_size, void* d_ws, size_t ws_size,
                              hipStream_t stream) {
    const float* features = (const float*)d_in[0];
    const int*   src      = (const int*)d_in[1];
    const int*   dst      = (const int*)d_in[2];
    const float* W1       = (const float*)d_in[3];
    const float* b1       = (const float*)d_in[4];
    const float* W2       = (const float*)d_in[5];
    const float* b2       = (const float*)d_in[6];
    float*       out      = (float*)d_out;

    const int nNodes = in_sizes[0] / F;           // 100000
    const int nEdges = in_sizes[1];               // 1600000
    const int NBUCK = (nNodes + 511) >> BSH;      // 196 (<= 256)
    const int NBLK  = (nEdges + EPB - 1) / EPB;   // 196

    // ---- workspace carve-up (peak ~48.9 MiB; round-1 proved >=51.6 MiB works)
    char* ws = (char*)d_ws;
    auto align = [](size_t x) { return (x + 255) / 256 * 256; };
    int* bucketCount  = (int*)ws;    ws += align(256 * 4);
    int* bucketStart  = (int*)ws;    ws += align(257 * 4);
    int* bucketCursor = (int*)ws;    ws += align(256 * 4);
    int* blockHist    = (int*)ws;    ws += align((size_t)NBLK * 256 * 4);
    int* rowstart     = (int*)ws;    ws += align((size_t)(nNodes + 1) * 4);
    int* csr          = (int*)ws;    ws += align((size_t)nEdges * 4);
    __half* xh        = (__half*)ws; ws += align((size_t)nNodes * F * 2);
    float* agg        = (float*)ws;  ws += align((size_t)nNodes * F * 4);  // also h
    __half* t2h       = (__half*)ws; ws += align((size_t)nNodes * C * 2);
    unsigned* pairs   = (unsigned*)agg;  // 6.4 MB inside agg; dead before gather

    hipMemsetAsync(bucketCount, 0, 256 * sizeof(int), stream);

    // ---- features -> fp16 (independent of CSR build)
    to_half<<<(nNodes * F / 4 + 255) / 256, 256, 0, stream>>>(features, xh,
                                                              nNodes * F / 4);

    // ---- CSR build: bucketed, single-writer lines, packed u32 pairs
    hist_k<<<NBLK, 256, 0, stream>>>(dst, bucketCount, blockHist, nEdges);
    bucket_scan<<<1, 256, 0, stream>>>(bucketCount, bucketStart, bucketCursor);
    partition<<<NBLK, 256, 0, stream>>>(src, dst, blockHist, bucketCursor, pairs, nEdges);
    bucket_csr<<<NBUCK, 512, 0, stream>>>(pairs, bucketStart, rowstart, csr,
                                          nNodes, nEdges);

    // ---- layer 1: agg = mean_agg(xh); agg = relu(agg@W1 + b1) in-place
    gather_h<<<(nNodes + 3) / 4, 256, 0, stream>>>(xh, rowstart, csr, agg, nNodes);
    layer1_inplace<<<(nNodes + 3) / 4, 256, 0, stream>>>(agg, W1, b1, nNodes);

    // ---- layer 2 (W2 pushed through mean-agg): t2 = h@W2 (fp16); out = mean_agg(t2)+b2
    mm2h<<<(nNodes + 15) / 16, 256, 0, stream>>>(agg, W2, t2h, nNodes);
    gather16h<<<(nNodes + 3) / 4, 256, 0, stream>>>(t2h, rowstart, csr, b2, out, nNodes);
}